// Round 1
// baseline (382.860 us; speedup 1.0000x reference)
//
#include <hip/hip_runtime.h>

// ChannelLatentMixer: out[b, 0:64, :] = z[b]; out[b, 64:128, :] = mean over rows
// with same channel id. B=4096, C=32, N=64, D=128.
#define NB      4096
#define NCH     32
#define ND      8192    // 64*128 floats per z row-block
#define OUTROW  16384   // 2*ND floats per output row-block

// ---- kernel 1: build per-channel row lists ---------------------------------
__global__ void build_lists_kernel(const int* __restrict__ ch,
                                   int* __restrict__ counts,
                                   int* __restrict__ lists) {
    int b = blockIdx.x * blockDim.x + threadIdx.x;
    if (b < NB) {
        int c = ch[b];
        int pos = atomicAdd(&counts[c], 1);
        lists[c * NB + pos] = b;
    }
}

// ---- kernel 2: single-pass copy + reduce + broadcast -----------------------
// grid = NCH * 32 blocks of 64 threads. Block (c, chunk) owns a 256-float
// column slice [chunk*256, chunk*256+256) of the 8192-float row.
__global__ __launch_bounds__(64) void mixer_kernel(const float* __restrict__ z,
                                                   const int* __restrict__ counts,
                                                   const int* __restrict__ lists,
                                                   float* __restrict__ out) {
    const int c     = blockIdx.x >> 5;
    const int chunk = blockIdx.x & 31;
    const int off   = chunk * 256 + threadIdx.x * 4;   // float offset in row
    const int cnt   = counts[c];
    const int* __restrict__ lst = lists + c * NB;

    float4 acc = make_float4(0.f, 0.f, 0.f, 0.f);

    // pass 1: read z once, copy to z-half of out, accumulate channel sum.
    int i = 0;
    for (; i + 4 <= cnt; i += 4) {
        const int b0 = lst[i + 0];
        const int b1 = lst[i + 1];
        const int b2 = lst[i + 2];
        const int b3 = lst[i + 3];
        const float4 v0 = *(const float4*)(z + (long)b0 * ND + off);
        const float4 v1 = *(const float4*)(z + (long)b1 * ND + off);
        const float4 v2 = *(const float4*)(z + (long)b2 * ND + off);
        const float4 v3 = *(const float4*)(z + (long)b3 * ND + off);
        *(float4*)(out + (long)b0 * OUTROW + off) = v0;
        *(float4*)(out + (long)b1 * OUTROW + off) = v1;
        *(float4*)(out + (long)b2 * OUTROW + off) = v2;
        *(float4*)(out + (long)b3 * OUTROW + off) = v3;
        acc.x += (v0.x + v1.x) + (v2.x + v3.x);
        acc.y += (v0.y + v1.y) + (v2.y + v3.y);
        acc.z += (v0.z + v1.z) + (v2.z + v3.z);
        acc.w += (v0.w + v1.w) + (v2.w + v3.w);
    }
    for (; i < cnt; ++i) {
        const int b = lst[i];
        const float4 v = *(const float4*)(z + (long)b * ND + off);
        *(float4*)(out + (long)b * OUTROW + off) = v;
        acc.x += v.x; acc.y += v.y; acc.z += v.z; acc.w += v.w;
    }

    const float inv = 1.0f / fmaxf((float)cnt, 1.0f);
    const float4 m = make_float4(acc.x * inv, acc.y * inv, acc.z * inv, acc.w * inv);

    // pass 2: broadcast mean to aggr-half of out for every row of this channel.
    int j = 0;
    for (; j + 4 <= cnt; j += 4) {
        const int b0 = lst[j + 0];
        const int b1 = lst[j + 1];
        const int b2 = lst[j + 2];
        const int b3 = lst[j + 3];
        *(float4*)(out + (long)b0 * OUTROW + ND + off) = m;
        *(float4*)(out + (long)b1 * OUTROW + ND + off) = m;
        *(float4*)(out + (long)b2 * OUTROW + ND + off) = m;
        *(float4*)(out + (long)b3 * OUTROW + ND + off) = m;
    }
    for (; j < cnt; ++j) {
        const int b = lst[j];
        *(float4*)(out + (long)b * OUTROW + ND + off) = m;
    }
}

extern "C" void kernel_launch(void* const* d_in, const int* in_sizes, int n_in,
                              void* d_out, int out_size, void* d_ws, size_t ws_size,
                              hipStream_t stream) {
    const float* z  = (const float*)d_in[0];
    const int*   ch = (const int*)d_in[1];
    float*       out = (float*)d_out;

    // ws layout: [0,128) counts (32 ints, padded), [128, 128+NB*NCH*4) lists.
    int* counts = (int*)d_ws;
    int* lists  = (int*)((char*)d_ws + 128);

    hipMemsetAsync(counts, 0, 128, stream);
    build_lists_kernel<<<(NB + 255) / 256, 256, 0, stream>>>(ch, counts, lists);
    mixer_kernel<<<NCH * 32, 64, 0, stream>>>(z, counts, lists, out);
}